// Round 11
// baseline (901.122 us; speedup 1.0000x reference)
//
#include <hip/hip_runtime.h>
#include <math.h>

// Problem constants (fixed by reference setup_inputs)
#define NTOT 100
#define NQ   75
#define NP   25
#define CC   128
#define TT   8
#define VV   25
#define NCLS 5
#define NSUP 5
#define NQRY 15
#define ROW  (TT*VV*CC)   // 25600 floats per sample
#define TILE (VV*CC)      // 3200 floats per (n,t)
#define ROWS_Q 20000
#define ROWS_S 5000
#define RB_Q 625          // 20000/32 exact
#define RB_S 157          // ceil(5000/32)
#define GRID 400          // persistent blocks; capacity 512 (LDS 3/CU, regs 2/CU) >= 400

typedef __attribute__((ext_vector_type(8))) short short8;
typedef __attribute__((ext_vector_type(16))) float f32x16;

typedef union { uint4 u4; short8 s8; } pk_t;

__device__ __forceinline__ ushort f2bf(float f) {
    uint u = __float_as_uint(f);
    u += 0x7FFFu + ((u >> 16) & 1u);   // RNE
    return (ushort)(u >> 16);
}
__device__ __forceinline__ float bf2f(uint u16v) {
    return __uint_as_float(u16v << 16);
}
__device__ __forceinline__ uint pkbf(float a, float b) {
    return (uint)f2bf(a) | ((uint)f2bf(b) << 16);
}

// Manual grid barrier: per-block flags + monotone rounds. Flags are SIGNED:
// harness poison 0xAAAAAAAA < 0 => "not arrived" (no init pass needed).
// Bounded spin => broken barrier fails validation instead of hanging.
__device__ __forceinline__ void gridbar(int* flags, int round) {
    __syncthreads();
    __threadfence();   // agent-scope fence: flush writes device-wide (cross-XCD)
    if (threadIdx.x == 0)
        __hip_atomic_store(&flags[blockIdx.x], round, __ATOMIC_RELEASE, __HIP_MEMORY_SCOPE_AGENT);
    for (int j = threadIdx.x; j < GRID; j += 256) {
        int spins = 0;
        while (__hip_atomic_load(&flags[j], __ATOMIC_ACQUIRE, __HIP_MEMORY_SCOPE_AGENT) < round) {
            __builtin_amdgcn_s_sleep(1);
            if (++spins > 100000000) break;   // safety valve
        }
    }
    __threadfence();   // acquire side: invalidate stale cached lines
    __syncthreads();
}

// ============ single persistent kernel: proj -> attn -> dist -> loss ============
__global__ __launch_bounds__(256, 2) void k_fused(
    const float* __restrict__ input, const int* __restrict__ target,
    const float* __restrict__ Wq, const float* __restrict__ Wk,
    const float* __restrict__ Wv, const float* __restrict__ Wo,
    const float* __restrict__ bq, const float* __restrict__ bk,
    const float* __restrict__ bv, const float* __restrict__ bo,
    const float* __restrict__ ln_g,
    ushort* __restrict__ catC, ushort* __restrict__ Qf,
    ushort* __restrict__ Kf, ushort* __restrict__ Vf,
    float* __restrict__ att, float* __restrict__ distb,
    int* __restrict__ flags, float* __restrict__ out) {
    __shared__ union {
        struct {                        // phase 1 (~50.2 KB)
            ushort stage[32 * 132];
            ushort Wf[16384];
            ushort VtF[4096];
            int iscr[200];
        } proj;
        struct {                        // phase 2 (~47.1 KB)
            float catb[25 * 129];
            float red[2][50][65];
            ushort qls[4096];
        } attn;
        struct {                        // phases 3/4
            float part[4];
            float pl[4], po[4];
        } dist;
    } sm;

    int tid = threadIdx.x;
    int w = tid >> 6, lane = tid & 63, half = lane >> 5, l31 = lane & 31;

    // ================= phase 1: gather + projections =================
    if (tid < NTOT) sm.proj.iscr[tid] = target[tid];
    __syncthreads();
    if (tid < NTOT) {
        int ti = sm.proj.iscr[tid], rank = 0;
        for (int j = 0; j < NTOT; ++j) {
            int tj = sm.proj.iscr[j];
            rank += (tj < ti) || (tj == ti && j < tid);
        }
        sm.proj.iscr[100 + rank] = tid;
    }

    #define BUILDW(W) do {                                                       \
        for (int o = tid; o < 2048; o += 256) {                                  \
            int k8 = o >> 7, c = o & 127;                                        \
            uint4 pk;                                                            \
            pk.x = pkbf((W)[(k8*8+0)*128 + c], (W)[(k8*8+1)*128 + c]);           \
            pk.y = pkbf((W)[(k8*8+2)*128 + c], (W)[(k8*8+3)*128 + c]);           \
            pk.z = pkbf((W)[(k8*8+4)*128 + c], (W)[(k8*8+5)*128 + c]);           \
            pk.w = pkbf((W)[(k8*8+6)*128 + c], (W)[(k8*8+7)*128 + c]);           \
            int dst = (((c >> 5) * 8 + (k8 >> 1)) * 64 + ((c & 31) + 32 * (k8 & 1))) * 8; \
            *(uint4*)(sm.proj.Wf + dst) = pk;                                    \
        }                                                                        \
    } while (0)
    #define CHAIN(A, OUT) do {                                                   \
        const ushort* bp_ = sm.proj.Wf + w * 4096 + lane * 8;                    \
        _Pragma("unroll")                                                        \
        for (int ks = 0; ks < 8; ++ks) {                                         \
            short8 bf_ = *(const short8*)(bp_ + ks * 512);                       \
            OUT = __builtin_amdgcn_mfma_f32_32x32x16_bf16(A[ks], bf_, OUT, 0, 0, 0); \
        }                                                                        \
    } while (0)

    for (int ib = blockIdx.x; ib < RB_Q + RB_S; ib += GRID) {
        __syncthreads();   // protect previous item's LDS readers
        bool isQ = ib < RB_Q;
        int rowblk = isQ ? ib : ib - RB_Q;
        int rlimit = isQ ? ROWS_Q : ROWS_S;
        int g0 = rowblk * 32;
        int gend = min(g0 + 32, rlimit);

        for (int nn = g0 / 200; nn <= (gend - 1) / 200; ++nn) {
            int lo = max(g0 - nn * 200, 0);
            int hi = min(gend - 1 - nn * 200, 199);
            int len = hi - lo + 1;
            int nidx = isQ ? nn : (NQ + nn);
            int src;
            if (nidx < NQ) { int m = nidx / NQRY, qq = nidx - m * NQRY; src = sm.proj.iscr[100 + m * 20 + NSUP + qq]; }
            else           { int i2 = nidx - NQ; int m = i2 / NSUP, s = i2 - m * NSUP; src = sm.proj.iscr[100 + m * 20 + s]; }
            const float* inb = input + (size_t)src * ROW + lo;
            int rbase = nn * 200 + lo - g0;
            for (int idx = tid; idx < len * 128; idx += 256) {
                int c = idx / len, k = idx - c * len;
                sm.proj.stage[(rbase + k) * 132 + c] = f2bf(inb[c * 200 + k]);
            }
        }
        BUILDW(isQ ? Wq : Wk);
        __syncthreads();

        short8 af[8];
        #pragma unroll
        for (int ks = 0; ks < 8; ++ks)
            af[ks] = *(const short8*)&sm.proj.stage[l31 * 132 + ks * 16 + half * 8];

        if (isQ) {
            f32x16 Cm;
            #pragma unroll
            for (int r = 0; r < 16; ++r) Cm[r] = 0.f;
            CHAIN(af, Cm);
            float bcol = bq[w * 32 + l31];
            int c = w * 32 + l31;
            #pragma unroll
            for (int r = 0; r < 16; ++r) {
                int row = g0 + (r & 3) + 8 * (r >> 2) + 4 * half;
                int st = row / 25, vv = row - st * 25;
                size_t dst = (((size_t)st * 8 + (c >> 4)) * 64 + (vv + 32 * ((c >> 3) & 1))) * 8 + (c & 7);
                Qf[dst] = f2bf(Cm[r] + bcol);
            }
            uint* cc = (uint*)catC + (size_t)g0 * 64;
            for (int idx = tid; idx < 2048; idx += 256) {
                int row = idx >> 6, c2 = (idx & 63) * 2;
                cc[idx] = (uint)sm.proj.stage[row * 132 + c2]
                        | ((uint)sm.proj.stage[row * 132 + c2 + 1] << 16);
            }
        } else {
            {   // K
                f32x16 Cm;
                #pragma unroll
                for (int r = 0; r < 16; ++r) Cm[r] = 0.f;
                CHAIN(af, Cm);
                float bcol = bk[w * 32 + l31];
                int c = w * 32 + l31;
                #pragma unroll
                for (int r = 0; r < 16; ++r) {
                    int row = g0 + (r & 3) + 8 * (r >> 2) + 4 * half;
                    if (row < ROWS_S) {
                        int st = row / 25, vv = row - st * 25;
                        size_t dst = (((size_t)st * 8 + (c >> 4)) * 64 + (vv + 32 * ((c >> 3) & 1))) * 8 + (c & 7);
                        Kf[dst] = f2bf(Cm[r] + bcol);
                    }
                }
            }
            __syncthreads();
            BUILDW(Wv);
            __syncthreads();
            {   // Vt = supp@Wv + bv -> A-frags in VtF
                f32x16 Cm;
                #pragma unroll
                for (int r = 0; r < 16; ++r) Cm[r] = 0.f;
                CHAIN(af, Cm);
                float bcol = bv[w * 32 + l31];
                int c = w * 32 + l31;
                int ks2 = c >> 4, kh = (c >> 3) & 1, j2 = c & 7;
                #pragma unroll
                for (int r = 0; r < 16; ++r) {
                    int rowLocal = (r & 3) + 8 * (r >> 2) + 4 * half;
                    sm.proj.VtF[ks2 * 512 + (rowLocal + 32 * kh) * 8 + j2] = f2bf(Cm[r] + bcol);
                }
            }
            __syncthreads();
            BUILDW(Wo);
            __syncthreads();
            short8 a2[8];
            #pragma unroll
            for (int ks = 0; ks < 8; ++ks)
                a2[ks] = *(const short8*)&sm.proj.VtF[ks * 512 + lane * 8];
            {   // V = Vt @ Wo
                f32x16 Cm;
                #pragma unroll
                for (int r = 0; r < 16; ++r) Cm[r] = 0.f;
                CHAIN(a2, Cm);
                int c = w * 32 + l31;
                #pragma unroll
                for (int r = 0; r < 16; ++r) {
                    int row = g0 + (r & 3) + 8 * (r >> 2) + 4 * half;
                    if (row < ROWS_S) {
                        int tile = row / 25, vv = row - tile * 25;
                        size_t dst = ((((size_t)tile * 4 + (c >> 5)) * 2 + (vv >> 4)) * 64
                                      + ((c & 31) + 32 * ((vv & 15) >> 3))) * 8 + (vv & 7);
                        Vf[dst] = f2bf(Cm[r]);
                    }
                }
            }
        }
    }
    #undef CHAIN
    #undef BUILDW

    gridbar(flags, 1);

    // ================= phase 2: fused attention + residual + LN =================
    const float CEXP = (float)(1.4426950408889634 * 0.08838834764831845);
    int q = l31, wv = w;

    for (int pair = blockIdx.x; pair < NTOT * TT; pair += GRID) {
        __syncthreads();   // previous pair's LDS readers done
        int t = pair & 7;

        {
            const uint* cc = (const uint*)catC + (size_t)pair * 1600;
            for (int i2 = tid; i2 < 1600; i2 += 256) {
                uint u = cc[i2];
                int r = i2 >> 6, c2 = (i2 & 63) * 2;
                sm.attn.catb[r * 129 + c2]     = bf2f(u & 0xffffu) + bo[c2];
                sm.attn.catb[r * 129 + c2 + 1] = bf2f(u >> 16) + bo[c2 + 1];
            }
        }
        {
            const uint* qp = (const uint*)(Qf + (size_t)pair * 4096);
            uint* ql = (uint*)sm.attn.qls;
            for (int i2 = tid; i2 < 2048; i2 += 256) ql[i2] = qp[i2];
        }
        __syncthreads();

        int qc = q < 25 ? q : 24;
        float attsum[64];
        #pragma unroll
        for (int i = 0; i < 64; ++i) attsum[i] = 0.f;
        float Csc = 0.f;

        const ushort* kbase = Kf + (size_t)t * 4096 + lane * 8;
        short8 kf[8];
        #pragma unroll
        for (int ks = 0; ks < 8; ++ks)
            kf[ks] = *(const short8*)(kbase + (size_t)wv * 32768 + ks * 512);

        int cnt = (wv == 0) ? 7 : 6;
        for (int mi = 0; mi < cnt; ++mi) {
            int m = wv + 4 * mi;

            f32x16 S;
            #pragma unroll
            for (int r = 0; r < 16; ++r) S[r] = 0.f;
            #pragma unroll
            for (int ks = 0; ks < 8; ++ks) {
                short8 qv = *(const short8*)(sm.attn.qls + ks * 512 + lane * 8);
                S = __builtin_amdgcn_mfma_f32_32x32x16_bf16(kf[ks], qv, S, 0, 0, 0);
            }

            float p[16], mx = -3e38f;
            #pragma unroll
            for (int r = 0; r < 16; ++r) {
                int key = (r & 3) + 8 * (r >> 2) + 4 * half;
                float v = (key < 25) ? S[r] : -3e38f;
                p[r] = v; mx = fmaxf(mx, v);
            }
            mx = fmaxf(mx, __shfl_xor(mx, 32));
            float sum = 0.f;
            #pragma unroll
            for (int r = 0; r < 16; ++r) { p[r] = exp2f((p[r] - mx) * CEXP); sum += p[r]; }
            sum += __shfl_xor(sum, 32);
            float inv = 1.f / sum;

            const ushort* vp = Vf + ((size_t)(m * 8 + t)) * 4096 + lane * 8;
            short8 vf0 = *(const short8*)(vp);
            short8 vf1 = *(const short8*)(vp + 512);
            short8 vf2 = *(const short8*)(vp + 1024);
            short8 vf3 = *(const short8*)(vp + 1536);
            short8 vf4 = *(const short8*)(vp + 2048);
            short8 vf5 = *(const short8*)(vp + 2560);
            short8 vf6 = *(const short8*)(vp + 3072);
            short8 vf7 = *(const short8*)(vp + 3584);
            #pragma unroll
            for (int ks = 0; ks < 8; ++ks)
                kf[ks] = *(const short8*)(kbase + (size_t)(m + 4) * 32768 + ks * 512);

            uint o01   = pkbf(p[0] * inv,  p[1] * inv);
            uint o23   = pkbf(p[2] * inv,  p[3] * inv);
            uint o45   = pkbf(p[4] * inv,  p[5] * inv);
            uint o67   = pkbf(p[6] * inv,  p[7] * inv);
            uint o89   = pkbf(p[8] * inv,  p[9] * inv);
            uint o1011 = pkbf(p[10] * inv, p[11] * inv);
            uint o1213 = pkbf(p[12] * inv, p[13] * inv);
            uint o1415 = pkbf(p[14] * inv, p[15] * inv);
            bool h0 = (half == 0);
            uint rA = __shfl_xor(h0 ? o45 : o01, 32);
            uint rB = __shfl_xor(h0 ? o67 : o23, 32);
            uint rC = __shfl_xor(h0 ? o1213 : o89, 32);
            uint rD = __shfl_xor(h0 ? o1415 : o1011, 32);
            pk_t P0, P1;
            P0.u4 = h0 ? make_uint4(o01, o23, rA, rB) : make_uint4(rA, rB, o45, o67);
            P1.u4 = h0 ? make_uint4(o89, o1011, rC, rD) : make_uint4(rC, rD, o1213, o1415);
            short8 pb0 = P0.s8, pb1 = P1.s8;

            f32x16 ctx[4];
            #pragma unroll
            for (int mt = 0; mt < 4; ++mt) {
                #pragma unroll
                for (int r = 0; r < 16; ++r) ctx[mt][r] = 0.f;
            }
            ctx[0] = __builtin_amdgcn_mfma_f32_32x32x16_bf16(vf0, pb0, ctx[0], 0, 0, 0);
            ctx[0] = __builtin_amdgcn_mfma_f32_32x32x16_bf16(vf1, pb1, ctx[0], 0, 0, 0);
            ctx[1] = __builtin_amdgcn_mfma_f32_32x32x16_bf16(vf2, pb0, ctx[1], 0, 0, 0);
            ctx[1] = __builtin_amdgcn_mfma_f32_32x32x16_bf16(vf3, pb1, ctx[1], 0, 0, 0);
            ctx[2] = __builtin_amdgcn_mfma_f32_32x32x16_bf16(vf4, pb0, ctx[2], 0, 0, 0);
            ctx[2] = __builtin_amdgcn_mfma_f32_32x32x16_bf16(vf5, pb1, ctx[2], 0, 0, 0);
            ctx[3] = __builtin_amdgcn_mfma_f32_32x32x16_bf16(vf6, pb0, ctx[3], 0, 0, 0);
            ctx[3] = __builtin_amdgcn_mfma_f32_32x32x16_bf16(vf7, pb1, ctx[3], 0, 0, 0);

            float s1 = 0.f, s2 = 0.f;
            #pragma unroll
            for (int mt = 0; mt < 4; ++mt) {
                float t1 = 0.f, t2 = 0.f;
                #pragma unroll
                for (int r = 0; r < 16; ++r) {
                    int c = mt * 32 + (r & 3) + 8 * (r >> 2) + 4 * half;
                    float xv = ctx[mt][r] + sm.attn.catb[qc * 129 + c];
                    ctx[mt][r] = xv;
                    t1 += xv; t2 = fmaf(xv, xv, t2);
                }
                s1 += t1; s2 += t2;
            }
            s1 += __shfl_xor(s1, 32); s2 += __shfl_xor(s2, 32);
            float mu = s1 * (1.f / 128.f);
            float var = s2 * (1.f / 128.f) - mu * mu;
            var = fmaxf(var, 0.f);
            float rs = rsqrtf(var + 1e-12f);
            #pragma unroll
            for (int i = 0; i < 64; ++i)
                attsum[i] = fmaf(ctx[i >> 4][i & 15], rs, attsum[i]);
            Csc = fmaf(-mu, rs, Csc);
        }

        __syncthreads();
        int s = half * 25 + q;
        bool act = q < 25;
        if ((wv == 1 || wv == 3) && act) {
            float (*rg)[65] = sm.attn.red[wv >> 1];
            #pragma unroll
            for (int i = 0; i < 64; ++i) rg[s][i] = attsum[i];
            rg[s][64] = Csc;
        }
        __syncthreads();
        if ((wv == 0 || wv == 2) && act) {
            float (*rg)[65] = sm.attn.red[wv >> 1];
            #pragma unroll
            for (int i = 0; i < 64; ++i) attsum[i] += rg[s][i];
            Csc += rg[s][64];
        }
        __syncthreads();
        if (wv == 2 && act) {
            #pragma unroll
            for (int i = 0; i < 64; ++i) sm.attn.red[0][s][i] = attsum[i];
            sm.attn.red[0][s][64] = Csc;
        }
        __syncthreads();
        if (wv == 0 && act) {
            #pragma unroll
            for (int i = 0; i < 64; ++i) attsum[i] += sm.attn.red[0][s][i];
            Csc += sm.attn.red[0][s][64];
            float* ap = att + (size_t)pair * TILE + q * 128;
            #pragma unroll
            for (int mt = 0; mt < 4; ++mt) {
                #pragma unroll
                for (int rg4 = 0; rg4 < 4; ++rg4) {
                    int c0 = mt * 32 + 8 * rg4 + 4 * half;
                    int i0 = mt * 16 + rg4 * 4;
                    float4 o;
                    o.x = attsum[i0 + 0] + Csc; o.y = attsum[i0 + 1] + Csc;
                    o.z = attsum[i0 + 2] + Csc; o.w = attsum[i0 + 3] + Csc;
                    *(float4*)&ap[c0] = o;
                }
            }
        }
    }

    gridbar(flags, 2);

    // ================= phase 3: distances =================
    for (int b = blockIdx.x; b < NQ * NCLS; b += GRID) {
        __syncthreads();
        int i = b / 5, j = b - 5 * i;
        const float4* a  = (const float4*)(att + (size_t)i * ROW);
        const float4* s0 = (const float4*)(att + (size_t)(NQ + j * 5 + 0) * ROW);
        const float4* s1p = (const float4*)(att + (size_t)(NQ + j * 5 + 1) * ROW);
        const float4* s2p = (const float4*)(att + (size_t)(NQ + j * 5 + 2) * ROW);
        const float4* s3p = (const float4*)(att + (size_t)(NQ + j * 5 + 3) * ROW);
        const float4* s4p = (const float4*)(att + (size_t)(NQ + j * 5 + 4) * ROW);
        float d = 0.f;
        for (int e4 = tid; e4 < 6400; e4 += 256) {
            float4 av = a[e4];
            float4 q0 = s0[e4], q1 = s1p[e4], q2 = s2p[e4], q3 = s3p[e4], q4 = s4p[e4];
            float4 g4 = *(const float4*)(ln_g + (e4 & 31) * 4);
            float px = 0.2f * (q0.x + q1.x + q2.x + q3.x + q4.x);
            float py = 0.2f * (q0.y + q1.y + q2.y + q3.y + q4.y);
            float pz = 0.2f * (q0.z + q1.z + q2.z + q3.z + q4.z);
            float pw = 0.2f * (q0.w + q1.w + q2.w + q3.w + q4.w);
            float dx = av.x - px, dy = av.y - py, dz = av.z - pz, dw = av.w - pw;
            d = fmaf(g4.x * g4.x, dx * dx, d);
            d = fmaf(g4.y * g4.y, dy * dy, d);
            d = fmaf(g4.z * g4.z, dz * dz, d);
            d = fmaf(g4.w * g4.w, dw * dw, d);
        }
        #pragma unroll
        for (int msk = 32; msk >= 1; msk >>= 1) d += __shfl_xor(d, msk);
        if (lane == 0) sm.dist.part[wv] = d;
        __syncthreads();
        if (tid == 0)
            distb[b] = (sm.dist.part[0] + sm.dist.part[1]
                      + sm.dist.part[2] + sm.dist.part[3]) * (1.f / 625.f);
    }

    gridbar(flags, 3);

    // ================= phase 4: loss + accuracy (block 0) =================
    if (blockIdx.x == 0) {
        __syncthreads();
        float li = 0.f, ok = 0.f;
        if (tid < NQ) {
            float dd[5];
            #pragma unroll
            for (int jj = 0; jj < 5; ++jj) dd[jj] = distb[tid * 5 + jj];
            int cls = tid / NQRY;
            float mind = dd[0];
            int best = 0;
            #pragma unroll
            for (int jj = 1; jj < 5; ++jj) {
                if (dd[jj] < mind) mind = dd[jj];
                if (dd[jj] < dd[best]) best = jj;   // first-min == argmax(-d)
            }
            float sume = 0.f;
            #pragma unroll
            for (int jj = 0; jj < 5; ++jj) sume += expf(mind - dd[jj]);
            float lse = logf(sume) - mind;
            li = dd[cls] + lse;
            ok = (best == cls) ? 1.f : 0.f;
        }
        #pragma unroll
        for (int msk = 32; msk >= 1; msk >>= 1) {
            li += __shfl_xor(li, msk);
            ok += __shfl_xor(ok, msk);
        }
        if (lane == 0) { sm.dist.pl[wv] = li; sm.dist.po[wv] = ok; }
        __syncthreads();
        if (tid == 0) {
            out[0] = (sm.dist.pl[0] + sm.dist.pl[1] + sm.dist.pl[2] + sm.dist.pl[3]) / 75.f;
            out[1] = (sm.dist.po[0] + sm.dist.po[1] + sm.dist.po[2] + sm.dist.po[3]) / 75.f;
        }
    }
}

extern "C" void kernel_launch(void* const* d_in, const int* in_sizes, int n_in,
                              void* d_out, int out_size, void* d_ws, size_t ws_size,
                              hipStream_t stream) {
    const float* input = (const float*)d_in[0];
    const float* Wq   = (const float*)d_in[1];
    const float* bq   = (const float*)d_in[2];
    const float* Wk   = (const float*)d_in[3];
    const float* bk   = (const float*)d_in[4];
    const float* Wv   = (const float*)d_in[5];
    const float* bv   = (const float*)d_in[6];
    const float* Wo   = (const float*)d_in[7];
    const float* bo   = (const float*)d_in[8];
    const float* ln_g = (const float*)d_in[9];
    const float* ln_b = (const float*)d_in[10];  // cancels in the distance
    const int* target = (const int*)d_in[11];
    float* out = (float*)d_out;
    (void)ln_b;

    float* ws = (float*)d_ws;
    ushort* catC = (ushort*)ws;                              // 2,560,000 u16
    ushort* Qf   = catC + 2560000;                           // 3,276,800
    ushort* Kf   = Qf + 3276800;                             //   819,200
    ushort* Vf   = Kf + 819200;                              //   819,200 (K prefetch overrun pad)
    float*  att  = (float*)(Vf + 819200);                    // 100*25600 fp32
    float*  distb = att + 2560000;                           // 375
    int*    flags = (int*)(distb + 512);                     // 400 ints (poison-tolerant)
    // total ~25.2 MB

    k_fused<<<GRID, 256, 0, stream>>>(input, target, Wq, Wk, Wv, Wo,
                                      bq, bk, bv, bo, ln_g,
                                      catC, Qf, Kf, Vf, att, distb, flags, out);
}

// Round 12
// 185.199 us; speedup vs baseline: 4.8657x; 4.8657x over previous
//
#include <hip/hip_runtime.h>
#include <math.h>

// Problem constants (fixed by reference setup_inputs)
#define NTOT 100
#define NQ   75
#define NP   25
#define CC   128
#define TT   8
#define VV   25
#define NCLS 5
#define NSUP 5
#define NQRY 15
#define ROW  (TT*VV*CC)   // 25600 floats per sample
#define TILE (VV*CC)      // 3200 floats per (n,t)
#define ROWS_Q 20000
#define ROWS_S 5000
#define RB_Q 625          // 20000/32 exact
#define RB_S 157          // ceil(5000/32)

typedef __attribute__((ext_vector_type(8))) short short8;
typedef __attribute__((ext_vector_type(16))) float f32x16;

typedef union { uint4 u4; short8 s8; } pk_t;

__device__ __forceinline__ ushort f2bf(float f) {
    uint u = __float_as_uint(f);
    u += 0x7FFFu + ((u >> 16) & 1u);   // RNE
    return (ushort)(u >> 16);
}
__device__ __forceinline__ float bf2f(uint u16v) {
    return __uint_as_float(u16v << 16);
}
__device__ __forceinline__ uint pkbf(float a, float b) {
    return (uint)f2bf(a) | ((uint)f2bf(b) << 16);
}

// ============ kernel 1: fused gather + projections (R9, unchanged) ============
__global__ __launch_bounds__(256) void k_proj(
    const float* __restrict__ input, const int* __restrict__ target,
    const float* __restrict__ Wq, const float* __restrict__ Wk,
    const float* __restrict__ Wv, const float* __restrict__ Wo,
    const float* __restrict__ bq, const float* __restrict__ bk,
    const float* __restrict__ bv,
    ushort* __restrict__ catC, ushort* __restrict__ Qf,
    ushort* __restrict__ Kf, ushort* __restrict__ Vf,
    int* __restrict__ counter) {
    __shared__ ushort stage[32 * 132];
    __shared__ ushort Wf[16384];
    __shared__ ushort VtF[4096];
    __shared__ int iscr[200];

    int bid = blockIdx.x, tid = threadIdx.x;
    int w = tid >> 6, lane = tid & 63, half = lane >> 5, l31 = lane & 31;

    if (bid == 0 && tid == 0) *counter = 0;

    if (tid < NTOT) iscr[tid] = target[tid];
    __syncthreads();
    if (tid < NTOT) {
        int ti = iscr[tid], rank = 0;
        for (int j = 0; j < NTOT; ++j) {
            int tj = iscr[j];
            rank += (tj < ti) || (tj == ti && j < tid);
        }
        iscr[100 + rank] = tid;
    }
    __syncthreads();

    bool isQ = bid < RB_Q;
    int rowblk = isQ ? bid : bid - RB_Q;
    int rlimit = isQ ? ROWS_Q : ROWS_S;
    int g0 = rowblk * 32;
    int gend = min(g0 + 32, rlimit);

    for (int nn = g0 / 200; nn <= (gend - 1) / 200; ++nn) {
        int lo = max(g0 - nn * 200, 0);
        int hi = min(gend - 1 - nn * 200, 199);
        int len = hi - lo + 1;
        int nidx = isQ ? nn : (NQ + nn);
        int src;
        if (nidx < NQ) { int m = nidx / NQRY, qq = nidx - m * NQRY; src = iscr[100 + m * 20 + NSUP + qq]; }
        else           { int i2 = nidx - NQ; int m = i2 / NSUP, s = i2 - m * NSUP; src = iscr[100 + m * 20 + s]; }
        const float* inb = input + (size_t)src * ROW + lo;
        int rbase = nn * 200 + lo - g0;
        for (int idx = tid; idx < len * 128; idx += 256) {
            int c = idx / len, k = idx - c * len;
            stage[(rbase + k) * 132 + c] = f2bf(inb[c * 200 + k]);
        }
    }

    #define BUILDW(W) do {                                                       \
        for (int o = tid; o < 2048; o += 256) {                                  \
            int k8 = o >> 7, c = o & 127;                                        \
            uint4 pk;                                                            \
            pk.x = pkbf((W)[(k8*8+0)*128 + c], (W)[(k8*8+1)*128 + c]);           \
            pk.y = pkbf((W)[(k8*8+2)*128 + c], (W)[(k8*8+3)*128 + c]);           \
            pk.z = pkbf((W)[(k8*8+4)*128 + c], (W)[(k8*8+5)*128 + c]);           \
            pk.w = pkbf((W)[(k8*8+6)*128 + c], (W)[(k8*8+7)*128 + c]);           \
            int dst = (((c >> 5) * 8 + (k8 >> 1)) * 64 + ((c & 31) + 32 * (k8 & 1))) * 8; \
            *(uint4*)(Wf + dst) = pk;                                            \
        }                                                                        \
    } while (0)

    BUILDW(isQ ? Wq : Wk);
    __syncthreads();

    short8 af[8];
    #pragma unroll
    for (int ks = 0; ks < 8; ++ks)
        af[ks] = *(const short8*)&stage[l31 * 132 + ks * 16 + half * 8];

    #define CHAIN(A, OUT) do {                                                   \
        const ushort* bp_ = Wf + w * 4096 + lane * 8;                            \
        _Pragma("unroll")                                                        \
        for (int ks = 0; ks < 8; ++ks) {                                         \
            short8 bf_ = *(const short8*)(bp_ + ks * 512);                       \
            OUT = __builtin_amdgcn_mfma_f32_32x32x16_bf16(A[ks], bf_, OUT, 0, 0, 0); \
        }                                                                        \
    } while (0)

    if (isQ) {
        f32x16 Cm;
        #pragma unroll
        for (int r = 0; r < 16; ++r) Cm[r] = 0.f;
        CHAIN(af, Cm);
        float bcol = bq[w * 32 + l31];
        int c = w * 32 + l31;
        #pragma unroll
        for (int r = 0; r < 16; ++r) {
            int row = g0 + (r & 3) + 8 * (r >> 2) + 4 * half;
            int st = row / 25, vv = row - st * 25;
            size_t dst = (((size_t)st * 8 + (c >> 4)) * 64 + (vv + 32 * ((c >> 3) & 1))) * 8 + (c & 7);
            Qf[dst] = f2bf(Cm[r] + bcol);
        }
        uint* cc = (uint*)catC + (size_t)g0 * 64;
        for (int idx = tid; idx < 2048; idx += 256) {
            int row = idx >> 6, c2 = (idx & 63) * 2;
            cc[idx] = (uint)stage[row * 132 + c2] | ((uint)stage[row * 132 + c2 + 1] << 16);
        }
    } else {
        {
            f32x16 Cm;
            #pragma unroll
            for (int r = 0; r < 16; ++r) Cm[r] = 0.f;
            CHAIN(af, Cm);
            float bcol = bk[w * 32 + l31];
            int c = w * 32 + l31;
            #pragma unroll
            for (int r = 0; r < 16; ++r) {
                int row = g0 + (r & 3) + 8 * (r >> 2) + 4 * half;
                if (row < ROWS_S) {
                    int st = row / 25, vv = row - st * 25;
                    size_t dst = (((size_t)st * 8 + (c >> 4)) * 64 + (vv + 32 * ((c >> 3) & 1))) * 8 + (c & 7);
                    Kf[dst] = f2bf(Cm[r] + bcol);
                }
            }
        }
        __syncthreads();
        BUILDW(Wv);
        __syncthreads();
        {
            f32x16 Cm;
            #pragma unroll
            for (int r = 0; r < 16; ++r) Cm[r] = 0.f;
            CHAIN(af, Cm);
            float bcol = bv[w * 32 + l31];
            int c = w * 32 + l31;
            int ks2 = c >> 4, kh = (c >> 3) & 1, j2 = c & 7;
            #pragma unroll
            for (int r = 0; r < 16; ++r) {
                int rowLocal = (r & 3) + 8 * (r >> 2) + 4 * half;
                VtF[ks2 * 512 + (rowLocal + 32 * kh) * 8 + j2] = f2bf(Cm[r] + bcol);
            }
        }
        __syncthreads();
        BUILDW(Wo);
        __syncthreads();
        short8 a2[8];
        #pragma unroll
        for (int ks = 0; ks < 8; ++ks)
            a2[ks] = *(const short8*)&VtF[ks * 512 + lane * 8];
        {
            f32x16 Cm;
            #pragma unroll
            for (int r = 0; r < 16; ++r) Cm[r] = 0.f;
            CHAIN(a2, Cm);
            int c = w * 32 + l31;
            #pragma unroll
            for (int r = 0; r < 16; ++r) {
                int row = g0 + (r & 3) + 8 * (r >> 2) + 4 * half;
                if (row < ROWS_S) {
                    int tile = row / 25, vv = row - tile * 25;
                    size_t dst = ((((size_t)tile * 4 + (c >> 5)) * 2 + (vv >> 4)) * 64
                                  + ((c & 31) + 32 * ((vv & 15) >> 3))) * 8 + (vv & 7);
                    Vf[dst] = f2bf(Cm[r]);
                }
            }
        }
    }
    #undef CHAIN
    #undef BUILDW
}

// ============ kernel 2: MFMA fused attention + residual + LN ============
// R9 body with LDS cut 47 KB -> ~21 KB: epilogue `red` buffer unioned over
// the m-loop state (catb+qls, disjoint lifetimes); reduction through one
// 50x66 buffer in 3 serial store/add rounds. VGPR=128 => HW can now run
// 4 blocks/CU (LDS was the old limiter at 3).
__global__ __launch_bounds__(256, 2) void k_attn(
    const ushort* __restrict__ Qf, const ushort* __restrict__ Kf,
    const ushort* __restrict__ Vf, const ushort* __restrict__ catC,
    const float* __restrict__ bo, float* __restrict__ att) {
    __shared__ union {
        struct {                       // m-loop state (~20.9 KB)
            float catb[25 * 129];
            ushort qls[4096];
        } loop;
        float red[50][66];             // epilogue (~13.2 KB), aliased
    } sm;

    int pair = blockIdx.x;                    // n*8 + t
    int t = pair & 7;
    int tid = threadIdx.x;
    int wv = tid >> 6, lane = tid & 63;
    int q = lane & 31, half = lane >> 5;

    {
        const uint* cc = (const uint*)catC + (size_t)pair * 1600;
        for (int i2 = tid; i2 < 1600; i2 += 256) {
            uint u = cc[i2];
            int r = i2 >> 6, c2 = (i2 & 63) * 2;
            sm.loop.catb[r * 129 + c2]     = bf2f(u & 0xffffu) + bo[c2];
            sm.loop.catb[r * 129 + c2 + 1] = bf2f(u >> 16) + bo[c2 + 1];
        }
    }
    {
        const uint* qp = (const uint*)(Qf + (size_t)pair * 4096);
        uint* ql = (uint*)sm.loop.qls;
        for (int i2 = tid; i2 < 2048; i2 += 256) ql[i2] = qp[i2];
    }
    __syncthreads();

    int qc = q < 25 ? q : 24;
    float attsum[64];
    #pragma unroll
    for (int i = 0; i < 64; ++i) attsum[i] = 0.f;
    float Csc = 0.f;

    const float CEXP = (float)(1.4426950408889634 * 0.08838834764831845);

    const ushort* kbase = Kf + (size_t)t * 4096 + lane * 8;
    short8 kf[8];
    #pragma unroll
    for (int ks = 0; ks < 8; ++ks)
        kf[ks] = *(const short8*)(kbase + (size_t)wv * 32768 + ks * 512);

    int cnt = (wv == 0) ? 7 : 6;
    for (int mi = 0; mi < cnt; ++mi) {
        int m = wv + 4 * mi;

        f32x16 S;
        #pragma unroll
        for (int r = 0; r < 16; ++r) S[r] = 0.f;
        #pragma unroll
        for (int ks = 0; ks < 8; ++ks) {
            short8 qv = *(const short8*)(sm.loop.qls + ks * 512 + lane * 8);
            S = __builtin_amdgcn_mfma_f32_32x32x16_bf16(kf[ks], qv, S, 0, 0, 0);
        }

        float p[16], mx = -3e38f;
        #pragma unroll
        for (int r = 0; r < 16; ++r) {
            int key = (r & 3) + 8 * (r >> 2) + 4 * half;
            float v = (key < 25) ? S[r] : -3e38f;
            p[r] = v; mx = fmaxf(mx, v);
        }
        mx = fmaxf(mx, __shfl_xor(mx, 32));
        float sum = 0.f;
        #pragma unroll
        for (int r = 0; r < 16; ++r) { p[r] = exp2f((p[r] - mx) * CEXP); sum += p[r]; }
        sum += __shfl_xor(sum, 32);
        float inv = 1.f / sum;

        const ushort* vp = Vf + ((size_t)(m * 8 + t)) * 4096 + lane * 8;
        short8 vf0 = *(const short8*)(vp);
        short8 vf1 = *(const short8*)(vp + 512);
        short8 vf2 = *(const short8*)(vp + 1024);
        short8 vf3 = *(const short8*)(vp + 1536);
        short8 vf4 = *(const short8*)(vp + 2048);
        short8 vf5 = *(const short8*)(vp + 2560);
        short8 vf6 = *(const short8*)(vp + 3072);
        short8 vf7 = *(const short8*)(vp + 3584);
        #pragma unroll
        for (int ks = 0; ks < 8; ++ks)
            kf[ks] = *(const short8*)(kbase + (size_t)(m + 4) * 32768 + ks * 512);

        uint o01   = pkbf(p[0] * inv,  p[1] * inv);
        uint o23   = pkbf(p[2] * inv,  p[3] * inv);
        uint o45   = pkbf(p[4] * inv,  p[5] * inv);
        uint o67   = pkbf(p[6] * inv,  p[7] * inv);
        uint o89   = pkbf(p[8] * inv,  p[9] * inv);
        uint o1011 = pkbf(p[10] * inv, p[11] * inv);
        uint o1213 = pkbf(p[12] * inv, p[13] * inv);
        uint o1415 = pkbf(p[14] * inv, p[15] * inv);
        bool h0 = (half == 0);
        uint rA = __shfl_xor(h0 ? o45 : o01, 32);
        uint rB = __shfl_xor(h0 ? o67 : o23, 32);
        uint rC = __shfl_xor(h0 ? o1213 : o89, 32);
        uint rD = __shfl_xor(h0 ? o1415 : o1011, 32);
        pk_t P0, P1;
        P0.u4 = h0 ? make_uint4(o01, o23, rA, rB) : make_uint4(rA, rB, o45, o67);
        P1.u4 = h0 ? make_uint4(o89, o1011, rC, rD) : make_uint4(rC, rD, o1213, o1415);
        short8 pb0 = P0.s8, pb1 = P1.s8;

        f32x16 ctx[4];
        #pragma unroll
        for (int mt = 0; mt < 4; ++mt) {
            #pragma unroll
            for (int r = 0; r < 16; ++r) ctx[mt][r] = 0.f;
        }
        ctx[0] = __builtin_amdgcn_mfma_f32_32x32x16_bf16(vf0, pb0, ctx[0], 0, 0, 0);
        ctx[0] = __builtin_amdgcn_mfma_f32_32x32x16_bf16(vf1, pb1, ctx[0], 0, 0, 0);
        ctx[1] = __builtin_amdgcn_mfma_f32_32x32x16_bf16(vf2, pb0, ctx[1], 0, 0, 0);
        ctx[1] = __builtin_amdgcn_mfma_f32_32x32x16_bf16(vf3, pb1, ctx[1], 0, 0, 0);
        ctx[2] = __builtin_amdgcn_mfma_f32_32x32x16_bf16(vf4, pb0, ctx[2], 0, 0, 0);
        ctx[2] = __builtin_amdgcn_mfma_f32_32x32x16_bf16(vf5, pb1, ctx[2], 0, 0, 0);
        ctx[3] = __builtin_amdgcn_mfma_f32_32x32x16_bf16(vf6, pb0, ctx[3], 0, 0, 0);
        ctx[3] = __builtin_amdgcn_mfma_f32_32x32x16_bf16(vf7, pb1, ctx[3], 0, 0, 0);

        float s1 = 0.f, s2 = 0.f;
        #pragma unroll
        for (int mt = 0; mt < 4; ++mt) {
            float t1 = 0.f, t2 = 0.f;
            #pragma unroll
            for (int r = 0; r < 16; ++r) {
                int c = mt * 32 + (r & 3) + 8 * (r >> 2) + 4 * half;
                float xv = ctx[mt][r] + sm.loop.catb[qc * 129 + c];
                ctx[mt][r] = xv;
                t1 += xv; t2 = fmaf(xv, xv, t2);
            }
            s1 += t1; s2 += t2;
        }
        s1 += __shfl_xor(s1, 32); s2 += __shfl_xor(s2, 32);
        float mu = s1 * (1.f / 128.f);
        float var = s2 * (1.f / 128.f) - mu * mu;
        var = fmaxf(var, 0.f);
        float rs = rsqrtf(var + 1e-12f);
        #pragma unroll
        for (int i = 0; i < 64; ++i)
            attsum[i] = fmaf(ctx[i >> 4][i & 15], rs, attsum[i]);
        Csc = fmaf(-mu, rs, Csc);
    }

    // ---- epilogue: 3 serial store/add rounds through one aliased buffer ----
    __syncthreads();   // all waves done with m-loop; catb/qls dead, red live
    int s = half * 25 + q;
    bool act = q < 25;
    if (wv == 3 && act) {
        #pragma unroll
        for (int i = 0; i < 64; ++i) sm.red[s][i] = attsum[i];
        sm.red[s][64] = Csc;
    }
    __syncthreads();
    if (wv == 2 && act) {
        #pragma unroll
        for (int i = 0; i < 64; ++i) attsum[i] += sm.red[s][i];
        Csc += sm.red[s][64];
    }
    __syncthreads();
    if (wv == 2 && act) {
        #pragma unroll
        for (int i = 0; i < 64; ++i) sm.red[s][i] = attsum[i];
        sm.red[s][64] = Csc;
    }
    __syncthreads();
    if (wv == 0 && act) {
        #pragma unroll
        for (int i = 0; i < 64; ++i) attsum[i] += sm.red[s][i];
        Csc += sm.red[s][64];
    }
    __syncthreads();
    if (wv == 1 && act) {
        #pragma unroll
        for (int i = 0; i < 64; ++i) sm.red[s][i] = attsum[i];
        sm.red[s][64] = Csc;
    }
    __syncthreads();
    if (wv == 0 && act) {
        #pragma unroll
        for (int i = 0; i < 64; ++i) attsum[i] += sm.red[s][i];
        Csc += sm.red[s][64];
        float* ap = att + (size_t)pair * TILE + q * 128;
        #pragma unroll
        for (int mt = 0; mt < 4; ++mt) {
            #pragma unroll
            for (int rg4 = 0; rg4 < 4; ++rg4) {
                int c0 = mt * 32 + 8 * rg4 + 4 * half;
                int i0 = mt * 16 + rg4 * 4;
                float4 o;
                o.x = attsum[i0 + 0] + Csc; o.y = attsum[i0 + 1] + Csc;
                o.z = attsum[i0 + 2] + Csc; o.w = attsum[i0 + 3] + Csc;
                *(float4*)&ap[c0] = o;
            }
        }
    }
}

// ============ kernel 3: fused distances + log-softmax loss/acc (R9, unchanged) ============
__global__ __launch_bounds__(256) void k_dist_loss(
    const float* __restrict__ att, const float* __restrict__ ln_g,
    float* __restrict__ dist, int* __restrict__ counter,
    float* __restrict__ out) {
    int b = blockIdx.x;
    int i = b / 5, j = b - 5 * i;
    const float4* a  = (const float4*)(att + (size_t)i * ROW);
    const float4* s0 = (const float4*)(att + (size_t)(NQ + j * 5 + 0) * ROW);
    const float4* s1p = (const float4*)(att + (size_t)(NQ + j * 5 + 1) * ROW);
    const float4* s2p = (const float4*)(att + (size_t)(NQ + j * 5 + 2) * ROW);
    const float4* s3p = (const float4*)(att + (size_t)(NQ + j * 5 + 3) * ROW);
    const float4* s4p = (const float4*)(att + (size_t)(NQ + j * 5 + 4) * ROW);
    float d = 0.f;
    for (int e4 = threadIdx.x; e4 < 6400; e4 += 256) {
        float4 av = a[e4];
        float4 q0 = s0[e4], q1 = s1p[e4], q2 = s2p[e4], q3 = s3p[e4], q4 = s4p[e4];
        float4 g4 = *(const float4*)(ln_g + (e4 & 31) * 4);
        float px = 0.2f * (q0.x + q1.x + q2.x + q3.x + q4.x);
        float py = 0.2f * (q0.y + q1.y + q2.y + q3.y + q4.y);
        float pz = 0.2f * (q0.z + q1.z + q2.z + q3.z + q4.z);
        float pw = 0.2f * (q0.w + q1.w + q2.w + q3.w + q4.w);
        float dx = av.x - px, dy = av.y - py, dz = av.z - pz, dw = av.w - pw;
        d = fmaf(g4.x * g4.x, dx * dx, d);
        d = fmaf(g4.y * g4.y, dy * dy, d);
        d = fmaf(g4.z * g4.z, dz * dz, d);
        d = fmaf(g4.w * g4.w, dw * dw, d);
    }
    #pragma unroll
    for (int msk = 32; msk >= 1; msk >>= 1) d += __shfl_xor(d, msk);
    __shared__ float part[4];
    __shared__ int lastFlag;
    int lane = threadIdx.x & 63, wv = threadIdx.x >> 6;
    if (lane == 0) part[wv] = d;
    __syncthreads();
    if (threadIdx.x == 0) {
        float total = (part[0] + part[1] + part[2] + part[3]) * (1.f / 625.f);
        __hip_atomic_store(&dist[b], total, __ATOMIC_RELEASE, __HIP_MEMORY_SCOPE_AGENT);
        int tk = __hip_atomic_fetch_add(counter, 1, __ATOMIC_ACQ_REL, __HIP_MEMORY_SCOPE_AGENT);
        lastFlag = (tk == 374);
    }
    __syncthreads();
    if (!lastFlag) return;

    int iq = threadIdx.x;
    float li = 0.f, ok = 0.f;
    if (iq < NQ) {
        float dd[5];
        #pragma unroll
        for (int jj = 0; jj < 5; ++jj)
            dd[jj] = __hip_atomic_load(&dist[iq * 5 + jj], __ATOMIC_ACQUIRE, __HIP_MEMORY_SCOPE_AGENT);
        int cls = iq / NQRY;
        float mind = dd[0];
        int best = 0;
        #pragma unroll
        for (int jj = 1; jj < 5; ++jj) {
            if (dd[jj] < mind) mind = dd[jj];
            if (dd[jj] < dd[best]) best = jj;
        }
        float sume = 0.f;
        #pragma unroll
        for (int jj = 0; jj < 5; ++jj) sume += expf(mind - dd[jj]);
        float lse = logf(sume) - mind;
        li = dd[cls] + lse;
        ok = (best == cls) ? 1.f : 0.f;
    }
    #pragma unroll
    for (int msk = 32; msk >= 1; msk >>= 1) {
        li += __shfl_xor(li, msk);
        ok += __shfl_xor(ok, msk);
    }
    if (lane == 0) { part[wv] = li; part[wv + 2] = ok; }
    __syncthreads();
    if (threadIdx.x == 0) {
        out[0] = (part[0] + part[1]) / 75.f;
        out[1] = (part[2] + part[3]) / 75.f;
    }
}

extern "C" void kernel_launch(void* const* d_in, const int* in_sizes, int n_in,
                              void* d_out, int out_size, void* d_ws, size_t ws_size,
                              hipStream_t stream) {
    const float* input = (const float*)d_in[0];
    const float* Wq   = (const float*)d_in[1];
    const float* bq   = (const float*)d_in[2];
    const float* Wk   = (const float*)d_in[3];
    const float* bk   = (const float*)d_in[4];
    const float* Wv   = (const float*)d_in[5];
    const float* bv   = (const float*)d_in[6];
    const float* Wo   = (const float*)d_in[7];
    const float* bo   = (const float*)d_in[8];
    const float* ln_g = (const float*)d_in[9];
    const float* ln_b = (const float*)d_in[10];  // cancels in the distance
    const int* target = (const int*)d_in[11];
    float* out = (float*)d_out;
    (void)ln_b;

    float* ws = (float*)d_ws;
    ushort* catC = (ushort*)ws;                              // 2,560,000 u16
    ushort* Qf   = catC + 2560000;                           // 3,276,800
    ushort* Kf   = Qf + 3276800;                             //   819,200
    ushort* Vf   = Kf + 819200;                              //   819,200 (K prefetch overrun pad)
    float*  att  = (float*)(Vf + 819200);                    // 100*25600 fp32
    float*  distb = att + 2560000;                           // 375
    int*    counter = (int*)(distb + 512);
    // total ~25.2 MB

    k_proj<<<RB_Q + RB_S, 256, 0, stream>>>(input, target, Wq, Wk, Wv, Wo, bq, bk, bv,
                                            catC, Qf, Kf, Vf, counter);
    k_attn<<<800, 256, 0, stream>>>(Qf, Kf, Vf, catC, bo, att);
    k_dist_loss<<<375, 256, 0, stream>>>(att, ln_g, distb, counter, out);
}